// Round 1
// baseline (217.986 us; speedup 1.0000x reference)
//
#include <hip/hip_runtime.h>
#include <hip/hip_bf16.h>
#include <cstddef>

// Problem constants
#define Bsz 16
#define Nn  8
#define Ll  64
#define Ss  32
#define Dd  256
#define Hh  128

__device__ __forceinline__ float fast_tanh(float x) {
    float e = __expf(2.0f * x);
    return 1.0f - 2.0f / (e + 1.0f);
}
__device__ __forceinline__ float sigmoidf_(float x) {
    return 1.0f / (1.0f + __expf(-x));
}
__device__ __forceinline__ float wave_sum(float x) {
#pragma unroll
    for (int off = 32; off > 0; off >>= 1) x += __shfl_xor(x, off, 64);
    return x;
}
__device__ __forceinline__ float wave_max(float x) {
#pragma unroll
    for (int off = 32; off > 0; off >>= 1) x = fmaxf(x, __shfl_xor(x, off, 64));
    return x;
}

// ---------------- transpose all weights (one launch) ----------------
__device__ __forceinline__ void tr_elem(const float* __restrict__ src, float* __restrict__ dst,
                                        int R, int C, int ldo, int coff, int e) {
    int g = e % R;     // output fastest dim -> coalesced writes
    int k = e / R;
    dst[k * ldo + coff + g] = src[g * C + k];
}

__global__ __launch_bounds__(256) void transpose_all(
    const float* __restrict__ W, const float* __restrict__ U, const float* __restrict__ saW,
    const float* __restrict__ Wih_f, const float* __restrict__ Wih_b,
    const float* __restrict__ Whh_f, const float* __restrict__ Whh_b,
    float* __restrict__ WT, float* __restrict__ UT, float* __restrict__ saWT,
    float* __restrict__ WihT, float* __restrict__ WhhT)
{
    int e = blockIdx.x * 256 + threadIdx.x;
    if      (e < 65536)  tr_elem(W,     WT,            256, 256, 256,  0,   e);
    else if (e < 131072) tr_elem(U,     UT,            256, 256, 256,  0,   e - 65536);
    else if (e < 196608) tr_elem(saW,   saWT,          256, 256, 256,  0,   e - 131072);
    else if (e < 327680) tr_elem(Wih_f, WihT,          512, 256, 1024, 0,   e - 196608);
    else if (e < 458752) tr_elem(Wih_b, WihT,          512, 256, 1024, 512, e - 327680);
    else if (e < 524288) tr_elem(Whh_f, WhhT,          512, 128, 512,  0,   e - 458752);
    else                 tr_elem(Whh_b, WhhT + 65536,  512, 128, 512,  0,   e - 524288);
}

// ---------------- fp32 GEMM: C[m][n] = sum_k A[m*K+k] * BT[k*N+n] ----------------
// M,N multiples of 64, K multiple of 32. 256 threads, 64x64 tile, 4x4 microtile.
__global__ __launch_bounds__(256) void gemm_nt(const float* __restrict__ A,
                                               const float* __restrict__ BT,
                                               float* __restrict__ C, int M, int N, int K)
{
    __shared__ float As[64][44];   // [m][k], ld 44 floats (16B-aligned rows, 2-way max alias)
    __shared__ float Bs[32][68];   // [k][n], ld 68 floats
    const int tid = threadIdx.x;
    const int tx = tid & 15, ty = tid >> 4;
    const int m0 = blockIdx.y * 64, n0 = blockIdx.x * 64;
    const int ka = tid & 31, ma = tid >> 5;
    const int nb = tid & 63, kb = tid >> 6;
    float acc[4][4] = {};
    for (int kc = 0; kc < K; kc += 32) {
#pragma unroll
        for (int r = 0; r < 8; ++r)
            As[ma + r * 8][ka] = A[(size_t)(m0 + ma + r * 8) * K + kc + ka];
#pragma unroll
        for (int r = 0; r < 8; ++r)
            Bs[kb + r * 4][nb] = BT[(size_t)(kc + kb + r * 4) * N + n0 + nb];
        __syncthreads();
#pragma unroll
        for (int kk = 0; kk < 32; kk += 4) {
            float ar[4][4], br[4][4];
#pragma unroll
            for (int i = 0; i < 4; ++i) {
                float4 t = *(const float4*)&As[ty * 4 + i][kk];
                ar[i][0] = t.x; ar[i][1] = t.y; ar[i][2] = t.z; ar[i][3] = t.w;
            }
#pragma unroll
            for (int q = 0; q < 4; ++q) {
                float4 t = *(const float4*)&Bs[kk + q][tx * 4];
                br[q][0] = t.x; br[q][1] = t.y; br[q][2] = t.z; br[q][3] = t.w;
            }
#pragma unroll
            for (int q = 0; q < 4; ++q)
#pragma unroll
                for (int i = 0; i < 4; ++i)
#pragma unroll
                    for (int j = 0; j < 4; ++j)
                        acc[i][j] += ar[i][q] * br[q][j];
        }
        __syncthreads();
    }
#pragma unroll
    for (int i = 0; i < 4; ++i) {
        float4 o; o.x = acc[i][0]; o.y = acc[i][1]; o.z = acc[i][2]; o.w = acc[i][3];
        *(float4*)&C[(size_t)(m0 + ty * 4 + i) * N + n0 + tx * 4] = o;
    }
}

// ---------------- scores + softmax over L, write a[b,n,s,l] ----------------
// grid: B*N*S blocks of 64 threads (1 wave). bid = (b*8+n)*32 + s
__global__ __launch_bounds__(64) void scores_kernel(const float* __restrict__ Wx,
                                                    const float* __restrict__ Us,
                                                    const float* __restrict__ v,
                                                    float* __restrict__ a_buf)
{
    int bid = blockIdx.x;
    int s  = bid & 31;
    int bn = bid >> 5;           // b*8+n
    int b  = bn >> 3;
    int lane = threadIdx.x;
    const float* wx = Wx + (size_t)bn * Ll * Dd;
    const float* us = Us + ((size_t)b * Ss + s) * Dd;
    float4 v4 = *(const float4*)&v[lane * 4];
    float4 u4 = *(const float4*)&us[lane * 4];
    __shared__ float sc[64];
    for (int l = 0; l < Ll; ++l) {
        float4 w4 = *(const float4*)&wx[l * Dd + lane * 4];
        float t0 = fast_tanh(w4.x + u4.x);
        float t1 = fast_tanh(w4.y + u4.y);
        float t2 = fast_tanh(w4.z + u4.z);
        float t3 = fast_tanh(w4.w + u4.w);
        float p = t0 * v4.x + t1 * v4.y + t2 * v4.z + t3 * v4.w;
        p = wave_sum(p);
        if (lane == 0) sc[l] = p;
    }
    __syncthreads();
    float sv = sc[lane];
    float mx = wave_max(sv);
    float e = __expf(sv - mx);
    float sum = wave_sum(e);
    a_buf[(size_t)bid * 64 + lane] = e / sum;
}

// ---------------- abar = mean_s a ; sr[n][b][d] = sum_l abar[l]*x[b,n,l,d] ----------------
__global__ __launch_bounds__(256) void sr_kernel(const float* __restrict__ a_buf,
                                                 const float* __restrict__ x,
                                                 float* __restrict__ sr_nb)
{
    int bn = blockIdx.x;         // b*8+n
    int b = bn >> 3, n = bn & 7;
    int tid = threadIdx.x;
    __shared__ float abar[64];
    __shared__ float red[4][64];
    {
        int l = tid & 63, sg = tid >> 6;
        float p = 0.f;
        for (int s = sg * 8; s < sg * 8 + 8; ++s)
            p += a_buf[((size_t)bn * 32 + s) * 64 + l];
        red[sg][l] = p;
        __syncthreads();
        if (tid < 64)
            abar[tid] = (red[0][tid] + red[1][tid] + red[2][tid] + red[3][tid]) * (1.0f / 32.0f);
        __syncthreads();
    }
    float acc = 0.f;
    const float* xp = x + (size_t)bn * Ll * Dd;
    for (int l = 0; l < Ll; ++l)
        acc += abar[l] * xp[l * Dd + tid];
    sr_nb[((size_t)n * Bsz + b) * Dd + tid] = acc;
}

// ---------------- sequential BiLSTM: 32 blocks (dir*16+b) x 512 threads ----------------
__global__ __launch_bounds__(512) void lstm_kernel(const float* __restrict__ gx,
                                                   const float* __restrict__ WhhT,
                                                   const float* __restrict__ bih_f, const float* __restrict__ bhh_f,
                                                   const float* __restrict__ bih_b, const float* __restrict__ bhh_b,
                                                   float* __restrict__ h_out)
{
    int blk = blockIdx.x;
    int dir = blk >> 4, b = blk & 15;
    int g = threadIdx.x;
    const float* whhT = WhhT + (size_t)dir * (128 * 512);
    float w[128];
#pragma unroll
    for (int k = 0; k < 128; ++k) w[k] = whhT[k * 512 + g];
    float bias = (dir == 0) ? (bih_f[g] + bhh_f[g]) : (bih_b[g] + bhh_b[g]);
    __shared__ float h[128], c[128], gb[512];
    if (g < 128) { h[g] = 0.f; c[g] = 0.f; }
    __syncthreads();
    for (int t = 0; t < Nn; ++t) {
        int n = (dir == 0) ? t : (Nn - 1 - t);
        float pre = gx[((size_t)(n * Bsz + b)) * 1024 + dir * 512 + g] + bias;
#pragma unroll
        for (int k = 0; k < 128; ++k) pre += w[k] * h[k];
        float act;
        if (g < 256)      act = sigmoidf_(pre);   // i, f
        else if (g < 384) act = fast_tanh(pre);   // g
        else              act = sigmoidf_(pre);   // o
        gb[g] = act;
        __syncthreads();
        if (g < 128) {
            float i_ = gb[g], f_ = gb[128 + g], g_ = gb[256 + g], o_ = gb[384 + g];
            float cn = f_ * c[g] + i_ * g_;
            float hn = o_ * fast_tanh(cn);
            c[g] = cn; h[g] = hn;
            h_out[(((size_t)dir * Nn + n) * Bsz + b) * Hh + g] = hn;
        }
        __syncthreads();
    }
}

// ---------------- att_raw[b,n] = sum_e tanh(c.saW_e + sab_e)*sav_e ----------------
__global__ __launch_bounds__(256) void att_kernel(const float* __restrict__ h_out,
                                                  const float* __restrict__ saWT,
                                                  const float* __restrict__ sab,
                                                  const float* __restrict__ sav,
                                                  float* __restrict__ att_raw)
{
    int bn = blockIdx.x;
    int b = bn >> 3, n = bn & 7;
    int e = threadIdx.x;
    __shared__ float cvec[256];
    if (e < 128) cvec[e] = h_out[((size_t)(0 * Nn + n) * Bsz + b) * Hh + e];
    else         cvec[e] = h_out[((size_t)(1 * Nn + n) * Bsz + b) * Hh + (e - 128)];
    __syncthreads();
    float acc = sab[e];
    for (int d = 0; d < 256; ++d) acc += saWT[d * 256 + e] * cvec[d];
    float t = fast_tanh(acc) * sav[e];
    t = wave_sum(t);
    __shared__ float r[4];
    if ((e & 63) == 0) r[e >> 6] = t;
    __syncthreads();
    if (e == 0) att_raw[bn] = r[0] + r[1] + r[2] + r[3];
}

// ---------------- softmax over n + pooled output ----------------
__global__ __launch_bounds__(256) void pool_kernel(const float* __restrict__ h_out,
                                                   const float* __restrict__ att_raw,
                                                   float* __restrict__ out)
{
    int b = blockIdx.x;
    int d = threadIdx.x;
    float av[8];
    float mx = -1e30f;
#pragma unroll
    for (int n = 0; n < Nn; ++n) { av[n] = att_raw[b * Nn + n]; mx = fmaxf(mx, av[n]); }
    float sum = 0.f;
#pragma unroll
    for (int n = 0; n < Nn; ++n) { av[n] = __expf(av[n] - mx); sum += av[n]; }
    float inv = 1.0f / sum;
    float acc = 0.f;
#pragma unroll
    for (int n = 0; n < Nn; ++n) {
        float cn = (d < 128) ? h_out[((size_t)(0 * Nn + n) * Bsz + b) * Hh + d]
                             : h_out[((size_t)(1 * Nn + n) * Bsz + b) * Hh + (d - 128)];
        acc += av[n] * cn;
    }
    out[b * 256 + d] = acc * inv;
}

extern "C" void kernel_launch(void* const* d_in, const int* in_sizes, int n_in,
                              void* d_out, int out_size, void* d_ws, size_t ws_size,
                              hipStream_t stream) {
    const float* x     = (const float*)d_in[0];
    const float* s     = (const float*)d_in[1];
    const float* W     = (const float*)d_in[2];
    const float* U     = (const float*)d_in[3];
    const float* v     = (const float*)d_in[4];
    const float* Wih_f = (const float*)d_in[5];
    const float* Whh_f = (const float*)d_in[6];
    const float* bih_f = (const float*)d_in[7];
    const float* bhh_f = (const float*)d_in[8];
    const float* Wih_b = (const float*)d_in[9];
    const float* Whh_b = (const float*)d_in[10];
    const float* bih_b = (const float*)d_in[11];
    const float* bhh_b = (const float*)d_in[12];
    const float* saW   = (const float*)d_in[13];
    const float* sab   = (const float*)d_in[14];
    const float* sav   = (const float*)d_in[15];
    float* out = (float*)d_out;
    float* ws  = (float*)d_ws;

    float* WT      = ws;                  // 65536
    float* UT      = WT + 65536;          // 65536
    float* saWT    = UT + 65536;          // 65536
    float* WihT    = saWT + 65536;        // 256*1024 = 262144
    float* WhhT    = WihT + 262144;       // 2*128*512 = 131072
    float* Wx      = WhhT + 131072;       // 8192*256 = 2097152
    float* Us      = Wx + 2097152;        // 512*256 = 131072
    float* a_buf   = Us + 131072;         // 16*8*32*64 = 262144
    float* sr_nb   = a_buf + 262144;      // 8*16*256 = 32768
    float* gx      = sr_nb + 32768;       // 128*1024 = 131072
    float* hbuf    = gx + 131072;         // 2*8*16*128 = 32768
    float* att_raw = hbuf + 32768;        // 128

    // 1. transpose all weights
    hipLaunchKernelGGL(transpose_all, dim3(2304), dim3(256), 0, stream,
                       W, U, saW, Wih_f, Wih_b, Whh_f, Whh_b, WT, UT, saWT, WihT, WhhT);
    // 2. Wx = x @ W^T  (M=8192,N=256,K=256)
    hipLaunchKernelGGL(gemm_nt, dim3(4, 128), dim3(256), 0, stream, x, WT, Wx, 8192, 256, 256);
    // 3. Us = s @ U^T  (M=512,N=256,K=256)
    hipLaunchKernelGGL(gemm_nt, dim3(4, 8), dim3(256), 0, stream, s, UT, Us, 512, 256, 256);
    // 4. scores + softmax over L
    hipLaunchKernelGGL(scores_kernel, dim3(4096), dim3(64), 0, stream, Wx, Us, v, a_buf);
    // 5. sr[n][b][d]
    hipLaunchKernelGGL(sr_kernel, dim3(128), dim3(256), 0, stream, a_buf, x, sr_nb);
    // 6. gates_x = u @ [Wih_f^T | Wih_b^T]  (M=128,N=1024,K=256)
    hipLaunchKernelGGL(gemm_nt, dim3(16, 2), dim3(256), 0, stream, sr_nb, WihT, gx, 128, 1024, 256);
    // 7. sequential BiLSTM
    hipLaunchKernelGGL(lstm_kernel, dim3(32), dim3(512), 0, stream,
                       gx, WhhT, bih_f, bhh_f, bih_b, bhh_b, hbuf);
    // 8. self-attention scores
    hipLaunchKernelGGL(att_kernel, dim3(128), dim3(256), 0, stream, hbuf, saWT, sab, sav, att_raw);
    // 9. softmax + pool
    hipLaunchKernelGGL(pool_kernel, dim3(16), dim3(256), 0, stream, hbuf, att_raw, out);
}

// Round 2
// 200.948 us; speedup vs baseline: 1.0848x; 1.0848x over previous
//
#include <hip/hip_runtime.h>
#include <cstddef>

#define Bsz 16
#define Nn  8
#define Ll  64
#define Ss  32
#define Dd  256
#define Hh  128

#define LOG2E 1.4426950408889634f

__device__ __forceinline__ float rcp_f(float x)  { return __builtin_amdgcn_rcpf(x); }
__device__ __forceinline__ float exp2_f(float x) { return __builtin_amdgcn_exp2f(x); }

__device__ __forceinline__ float fast_tanh(float x) {
    // tanh(x) = 1 - 2/(exp2(2*log2e*x)+1); v_exp+v_rcp, ~1ulp each
    return 1.0f - 2.0f * rcp_f(exp2_f(x * (2.0f * LOG2E)) + 1.0f);
}
__device__ __forceinline__ float fast_sigmoid(float x) {
    return rcp_f(1.0f + exp2_f(-x * LOG2E));
}
__device__ __forceinline__ float wave_sum(float x) {
#pragma unroll
    for (int off = 32; off > 0; off >>= 1) x += __shfl_xor(x, off, 64);
    return x;
}
__device__ __forceinline__ float wave_max(float x) {
#pragma unroll
    for (int off = 32; off > 0; off >>= 1) x = fmaxf(x, __shfl_xor(x, off, 64));
    return x;
}

// ---------------- tiled transpose of weight matrices ----------------
// 64x64 tiles through LDS; coalesced global reads AND writes.
// blocks: 0-15 W, 16-31 U, 32-47 saW, 48-79 Wih_f, 80-111 Wih_b  (112 total)
__global__ __launch_bounds__(256) void transpose_all(
    const float* __restrict__ W, const float* __restrict__ U, const float* __restrict__ saW,
    const float* __restrict__ Wih_f, const float* __restrict__ Wih_b,
    float* __restrict__ WT, float* __restrict__ UT, float* __restrict__ saWT,
    float* __restrict__ WihT)
{
    __shared__ float ts[64][65];
    int blk = blockIdx.x, tid = threadIdx.x;
    const float* src; float* dst; int C, ldo, coff, t;
    if (blk < 16)      { src = W;     dst = WT;   C = 256; ldo = 256;  coff = 0;   t = blk;      }
    else if (blk < 32) { src = U;     dst = UT;   C = 256; ldo = 256;  coff = 0;   t = blk - 16; }
    else if (blk < 48) { src = saW;   dst = saWT; C = 256; ldo = 256;  coff = 0;   t = blk - 32; }
    else if (blk < 80) { src = Wih_f; dst = WihT; C = 256; ldo = 1024; coff = 0;   t = blk - 48; }
    else               { src = Wih_b; dst = WihT; C = 256; ldo = 1024; coff = 512; t = blk - 80; }
    int r0 = (t >> 2) * 64, c0 = (t & 3) * 64;
    int f = tid & 15, r = tid >> 4;
#pragma unroll
    for (int p = 0; p < 4; ++p) {
        int rr = r + 16 * p;
        float4 tv = *(const float4*)&src[(size_t)(r0 + rr) * C + c0 + 4 * f];
        ts[rr][4 * f + 0] = tv.x; ts[rr][4 * f + 1] = tv.y;
        ts[rr][4 * f + 2] = tv.z; ts[rr][4 * f + 3] = tv.w;
    }
    __syncthreads();
#pragma unroll
    for (int p = 0; p < 4; ++p) {
        int oc = (tid >> 4) + 16 * p;
        float4 o;
        o.x = ts[4 * f + 0][oc]; o.y = ts[4 * f + 1][oc];
        o.z = ts[4 * f + 2][oc]; o.w = ts[4 * f + 3][oc];
        *(float4*)&dst[(size_t)(c0 + oc) * ldo + coff + r0 + 4 * f] = o;
    }
}

// ---------------- fp32 GEMM: C[m][n] = sum_k A[m*K+k] * BT[k*N+n] ----------------
__global__ __launch_bounds__(256) void gemm_nt(const float* __restrict__ A,
                                               const float* __restrict__ BT,
                                               float* __restrict__ C, int M, int N, int K)
{
    __shared__ float As[64][44];
    __shared__ float Bs[32][68];
    const int tid = threadIdx.x;
    const int tx = tid & 15, ty = tid >> 4;
    const int m0 = blockIdx.y * 64, n0 = blockIdx.x * 64;
    const int ka = tid & 31, ma = tid >> 5;
    const int nb = tid & 63, kb = tid >> 6;
    float acc[4][4] = {};
    for (int kc = 0; kc < K; kc += 32) {
#pragma unroll
        for (int r = 0; r < 8; ++r)
            As[ma + r * 8][ka] = A[(size_t)(m0 + ma + r * 8) * K + kc + ka];
#pragma unroll
        for (int r = 0; r < 8; ++r)
            Bs[kb + r * 4][nb] = BT[(size_t)(kc + kb + r * 4) * N + n0 + nb];
        __syncthreads();
#pragma unroll
        for (int kk = 0; kk < 32; kk += 4) {
            float ar[4][4], br[4][4];
#pragma unroll
            for (int i = 0; i < 4; ++i) {
                float4 t = *(const float4*)&As[ty * 4 + i][kk];
                ar[i][0] = t.x; ar[i][1] = t.y; ar[i][2] = t.z; ar[i][3] = t.w;
            }
#pragma unroll
            for (int q = 0; q < 4; ++q) {
                float4 t = *(const float4*)&Bs[kk + q][tx * 4];
                br[q][0] = t.x; br[q][1] = t.y; br[q][2] = t.z; br[q][3] = t.w;
            }
#pragma unroll
            for (int q = 0; q < 4; ++q)
#pragma unroll
                for (int i = 0; i < 4; ++i)
#pragma unroll
                    for (int j = 0; j < 4; ++j)
                        acc[i][j] = fmaf(ar[i][q], br[q][j], acc[i][j]);
        }
        __syncthreads();
    }
#pragma unroll
    for (int i = 0; i < 4; ++i) {
        float4 o; o.x = acc[i][0]; o.y = acc[i][1]; o.z = acc[i][2]; o.w = acc[i][3];
        *(float4*)&C[(size_t)(m0 + ty * 4 + i) * N + n0 + tx * 4] = o;
    }
}

// ---------------- scores + softmax over L ----------------
// 256 blocks = (bn, s-half); 512 threads = 8 waves, each wave owns 2 s values.
// Wx tile staged ONCE in LDS; score = vsum - 2*sum_d v_d * rcp(exp2(c*(w+u))+1).
__global__ __launch_bounds__(512, 1) void scores_kernel(const float* __restrict__ Wx,
                                                        const float* __restrict__ Us,
                                                        const float* __restrict__ v,
                                                        float* __restrict__ a_buf)
{
    __shared__ float wx[64][260];
    __shared__ float us[16][256];
    __shared__ float sc[16][64];
    const int bid = blockIdx.x;
    const int bn = bid >> 1, sh = bid & 1;
    const int b = bn >> 3;
    const int tid = threadIdx.x;
    const int lane = tid & 63, w = tid >> 6;
    {
        const float* wxg = Wx + (size_t)bn * (Ll * Dd);
        int c = tid & 63, r0 = tid >> 6;
#pragma unroll
        for (int p = 0; p < 8; ++p) {
            int r = r0 + p * 8;
            float4 t = *(const float4*)&wxg[r * 256 + c * 4];
            *(float4*)&wx[r][c * 4] = t;
        }
        const float* usg = Us + ((size_t)b * Ss + sh * 16) * 256;
#pragma unroll
        for (int p = 0; p < 2; ++p) {
            int r = r0 + p * 8;
            float4 t = *(const float4*)&usg[r * 256 + c * 4];
            *(float4*)&us[r][c * 4] = t;
        }
    }
    __syncthreads();
    const float C2 = 2.0f * LOG2E;
    float4 v4 = *(const float4*)&v[lane * 4];
    float vsum = wave_sum(v4.x + v4.y + v4.z + v4.w);
    const int s0 = w * 2, s1 = s0 + 1;
    float4 ua = *(const float4*)&us[s0][lane * 4];
    float4 ub = *(const float4*)&us[s1][lane * 4];
    ua.x *= C2; ua.y *= C2; ua.z *= C2; ua.w *= C2;
    ub.x *= C2; ub.y *= C2; ub.z *= C2; ub.w *= C2;
    for (int l = 0; l < 64; ++l) {
        float4 wv = *(const float4*)&wx[l][lane * 4];
        float cx = wv.x * C2, cy = wv.y * C2, cz = wv.z * C2, cw = wv.w * C2;
        float a0 =       v4.x * rcp_f(exp2_f(cx + ua.x) + 1.0f);
        a0 = fmaf(v4.y, rcp_f(exp2_f(cy + ua.y) + 1.0f), a0);
        a0 = fmaf(v4.z, rcp_f(exp2_f(cz + ua.z) + 1.0f), a0);
        a0 = fmaf(v4.w, rcp_f(exp2_f(cw + ua.w) + 1.0f), a0);
        float a1 =       v4.x * rcp_f(exp2_f(cx + ub.x) + 1.0f);
        a1 = fmaf(v4.y, rcp_f(exp2_f(cy + ub.y) + 1.0f), a1);
        a1 = fmaf(v4.z, rcp_f(exp2_f(cz + ub.z) + 1.0f), a1);
        a1 = fmaf(v4.w, rcp_f(exp2_f(cw + ub.w) + 1.0f), a1);
        a0 = wave_sum(a0);
        a1 = wave_sum(a1);
        if (lane == 0) { sc[s0][l] = vsum - 2.0f * a0; sc[s1][l] = vsum - 2.0f * a1; }
    }
    __syncthreads();
    // softmax over l (lane = l), per-wave for its two s
    float sv0 = sc[s0][lane], sv1 = sc[s1][lane];
    float e0 = exp2_f((sv0 - wave_max(sv0)) * LOG2E);
    float e1 = exp2_f((sv1 - wave_max(sv1)) * LOG2E);
    float i0 = rcp_f(wave_sum(e0));
    float i1 = rcp_f(wave_sum(e1));
    float* ab = a_buf + ((size_t)bn * Ss + sh * 16) * 64;
    ab[s0 * 64 + lane] = e0 * i0;
    ab[s1 * 64 + lane] = e1 * i1;
}

// ---------------- abar = mean_s a ; sr[n][b][d] = sum_l abar[l]*x[b,n,l,d] ----------------
__global__ __launch_bounds__(256) void sr_kernel(const float* __restrict__ a_buf,
                                                 const float* __restrict__ x,
                                                 float* __restrict__ sr_nb)
{
    int bn = blockIdx.x;
    int b = bn >> 3, n = bn & 7;
    int tid = threadIdx.x;
    __shared__ float abar[64];
    __shared__ float red[4][64];
    {
        int l = tid & 63, sg = tid >> 6;
        float p = 0.f;
        for (int s = sg * 8; s < sg * 8 + 8; ++s)
            p += a_buf[((size_t)bn * 32 + s) * 64 + l];
        red[sg][l] = p;
        __syncthreads();
        if (tid < 64)
            abar[tid] = (red[0][tid] + red[1][tid] + red[2][tid] + red[3][tid]) * (1.0f / 32.0f);
        __syncthreads();
    }
    float acc = 0.f;
    const float* xp = x + (size_t)bn * Ll * Dd;
    for (int l = 0; l < Ll; ++l)
        acc = fmaf(abar[l], xp[l * Dd + tid], acc);
    sr_nb[((size_t)n * Bsz + b) * Dd + tid] = acc;
}

// ---------------- sequential BiLSTM: 32 blocks (dir*16+b) x 512 threads ----------------
__global__ __launch_bounds__(512) void lstm_kernel(const float* __restrict__ gx,
                                                   const float* __restrict__ Whh_f,
                                                   const float* __restrict__ Whh_b,
                                                   const float* __restrict__ bih_f, const float* __restrict__ bhh_f,
                                                   const float* __restrict__ bih_b, const float* __restrict__ bhh_b,
                                                   float* __restrict__ h_out)
{
    int blk = blockIdx.x;
    int dir = blk >> 4, b = blk & 15;
    int g = threadIdx.x;
    // thread g needs row g of Whh (contiguous 512B) — no transpose needed
    const float* wr = ((dir == 0) ? Whh_f : Whh_b) + (size_t)g * 128;
    float4 w4[32];
#pragma unroll
    for (int k = 0; k < 32; ++k) w4[k] = ((const float4*)wr)[k];
    float bias = (dir == 0) ? (bih_f[g] + bhh_f[g]) : (bih_b[g] + bhh_b[g]);
    __shared__ float h[128], c[128], gb[512];
    if (g < 128) { h[g] = 0.f; c[g] = 0.f; }
    __syncthreads();
    for (int t = 0; t < Nn; ++t) {
        int n = (dir == 0) ? t : (Nn - 1 - t);
        float a0 = gx[((size_t)(n * Bsz + b)) * 1024 + dir * 512 + g] + bias;
        float a1 = 0.f, a2 = 0.f, a3 = 0.f;
#pragma unroll
        for (int k = 0; k < 32; ++k) {
            float4 hv = *(const float4*)&h[k * 4];
            a0 = fmaf(w4[k].x, hv.x, a0);
            a1 = fmaf(w4[k].y, hv.y, a1);
            a2 = fmaf(w4[k].z, hv.z, a2);
            a3 = fmaf(w4[k].w, hv.w, a3);
        }
        float pre = (a0 + a1) + (a2 + a3);
        float act = (g < 256 || g >= 384) ? fast_sigmoid(pre) : fast_tanh(pre);
        gb[g] = act;
        __syncthreads();
        if (g < 128) {
            float i_ = gb[g], f_ = gb[128 + g], g_ = gb[256 + g], o_ = gb[384 + g];
            float cn = fmaf(f_, c[g], i_ * g_);
            float hn = o_ * fast_tanh(cn);
            c[g] = cn; h[g] = hn;
            h_out[(((size_t)dir * Nn + n) * Bsz + b) * Hh + g] = hn;
        }
        __syncthreads();
    }
}

// ---------------- fused self-attention scores + softmax + pool ----------------
__global__ __launch_bounds__(256) void attpool_kernel(const float* __restrict__ hbuf,
                                                      const float* __restrict__ saWT,
                                                      const float* __restrict__ sab,
                                                      const float* __restrict__ sav,
                                                      float* __restrict__ out)
{
    int b = blockIdx.x;
    int e = threadIdx.x;
    __shared__ float cvec[8][260];
    __shared__ float part[8][4];
#pragma unroll
    for (int n = 0; n < 8; ++n) {
        float val = (e < 128) ? hbuf[((size_t)(0 * Nn + n) * Bsz + b) * Hh + e]
                              : hbuf[((size_t)(1 * Nn + n) * Bsz + b) * Hh + (e - 128)];
        cvec[n][e] = val;
    }
    __syncthreads();
    float acc[8];
    float b0 = sab[e];
#pragma unroll
    for (int n = 0; n < 8; ++n) acc[n] = b0;
    for (int dq = 0; dq < 64; ++dq) {
        float w0 = saWT[(dq * 4 + 0) * 256 + e];
        float w1 = saWT[(dq * 4 + 1) * 256 + e];
        float w2 = saWT[(dq * 4 + 2) * 256 + e];
        float w3 = saWT[(dq * 4 + 3) * 256 + e];
#pragma unroll
        for (int n = 0; n < 8; ++n) {
            float4 cv = *(const float4*)&cvec[n][dq * 4];
            acc[n] = fmaf(w0, cv.x, acc[n]);
            acc[n] = fmaf(w1, cv.y, acc[n]);
            acc[n] = fmaf(w2, cv.z, acc[n]);
            acc[n] = fmaf(w3, cv.w, acc[n]);
        }
    }
    int w = e >> 6, lane = e & 63;
    float se = sav[e];
#pragma unroll
    for (int n = 0; n < 8; ++n) {
        float t = fast_tanh(acc[n]) * se;
        t = wave_sum(t);
        if (lane == 0) part[n][w] = t;
    }
    __syncthreads();
    float av[8], mx = -1e30f;
#pragma unroll
    for (int n = 0; n < 8; ++n) {
        av[n] = part[n][0] + part[n][1] + part[n][2] + part[n][3];
        mx = fmaxf(mx, av[n]);
    }
    float sum = 0.f;
#pragma unroll
    for (int n = 0; n < 8; ++n) { av[n] = exp2_f((av[n] - mx) * LOG2E); sum += av[n]; }
    float inv = rcp_f(sum);
    float acco = 0.f;
#pragma unroll
    for (int n = 0; n < 8; ++n) acco = fmaf(av[n], cvec[n][e], acco);
    out[b * 256 + e] = acco * inv;
}

extern "C" void kernel_launch(void* const* d_in, const int* in_sizes, int n_in,
                              void* d_out, int out_size, void* d_ws, size_t ws_size,
                              hipStream_t stream) {
    const float* x     = (const float*)d_in[0];
    const float* s     = (const float*)d_in[1];
    const float* W     = (const float*)d_in[2];
    const float* U     = (const float*)d_in[3];
    const float* v     = (const float*)d_in[4];
    const float* Wih_f = (const float*)d_in[5];
    const float* Whh_f = (const float*)d_in[6];
    const float* bih_f = (const float*)d_in[7];
    const float* bhh_f = (const float*)d_in[8];
    const float* Wih_b = (const float*)d_in[9];
    const float* Whh_b = (const float*)d_in[10];
    const float* bih_b = (const float*)d_in[11];
    const float* bhh_b = (const float*)d_in[12];
    const float* saW   = (const float*)d_in[13];
    const float* sab   = (const float*)d_in[14];
    const float* sav   = (const float*)d_in[15];
    float* out = (float*)d_out;
    float* ws  = (float*)d_ws;

    float* WT    = ws;                 // 65536
    float* UT    = WT + 65536;         // 65536
    float* saWT  = UT + 65536;         // 65536
    float* WihT  = saWT + 65536;       // 262144
    float* Wx    = WihT + 262144;      // 2097152
    float* Us    = Wx + 2097152;       // 131072
    float* a_buf = Us + 131072;        // 262144
    float* sr_nb = a_buf + 262144;     // 32768
    float* gx    = sr_nb + 32768;      // 131072
    float* hbuf  = gx + 131072;        // 32768

    hipLaunchKernelGGL(transpose_all, dim3(112), dim3(256), 0, stream,
                       W, U, saW, Wih_f, Wih_b, WT, UT, saWT, WihT);
    hipLaunchKernelGGL(gemm_nt, dim3(4, 128), dim3(256), 0, stream, x, WT, Wx, 8192, 256, 256);
    hipLaunchKernelGGL(gemm_nt, dim3(4, 8), dim3(256), 0, stream, s, UT, Us, 512, 256, 256);
    hipLaunchKernelGGL(scores_kernel, dim3(256), dim3(512), 0, stream, Wx, Us, v, a_buf);
    hipLaunchKernelGGL(sr_kernel, dim3(128), dim3(256), 0, stream, a_buf, x, sr_nb);
    hipLaunchKernelGGL(gemm_nt, dim3(16, 2), dim3(256), 0, stream, sr_nb, WihT, gx, 128, 1024, 256);
    hipLaunchKernelGGL(lstm_kernel, dim3(32), dim3(512), 0, stream,
                       gx, Whh_f, Whh_b, bih_f, bhh_f, bih_b, bhh_b, hbuf);
    hipLaunchKernelGGL(attpool_kernel, dim3(16), dim3(256), 0, stream, hbuf, saWT, sab, sav, out);
}